// Round 1
// baseline (255.293 us; speedup 1.0000x reference)
//
#include <hip/hip_runtime.h>
#include <cstdint>

#define N_TOK   32768
#define DIM     1024
#define NEXP    64
#define TM      128
#define BK      32
#define KITERS  (DIM / BK)   // 32
#define NTHR    256

typedef uint32_t __attribute__((address_space(3))) lds_u32_t;
typedef const uint32_t __attribute__((address_space(1))) glb_u32_t;

__device__ __forceinline__ void gload16(const float* g, float4* l) {
  // async global->LDS, 16 bytes per lane (dest must be wave-uniform base + lane*16)
  __builtin_amdgcn_global_load_lds((glb_u32_t*)g, (lds_u32_t*)l, 16, 0, 0);
}

// XOR swizzle: row r, float4-slot s (0..7) stored at float4 position r*8 + (s ^ ((r>>2)&7)).
// Spreads rows-8-apart (token axis) and rows-4-apart (expert axis) across bank quads.
__device__ __forceinline__ int swz(int r, int s) { return (r << 3) + (s ^ ((r >> 2) & 7)); }

__launch_bounds__(NTHR, 1)
__global__ void router_kernel(const float* __restrict__ x,
                              const float* __restrict__ Wg,
                              float* __restrict__ out,
                              unsigned int* __restrict__ cnt_g,
                              float* __restrict__ sp_g) {
  __shared__ float4 Xs4[2][TM * BK / 4];     // 2 x 16 KB
  __shared__ float4 Ws4[2][NEXP * BK / 4];   // 2 x 8 KB
  __shared__ float  L[TM * 65];              // logits -> probs, stride 65 (bank-conflict-free scalar access)
  __shared__ float  Linv[TM];
  __shared__ float  colpart[4 * NEXP];
  __shared__ unsigned int cnt_s[NEXP];

  const int tid  = threadIdx.x;
  const int tx   = tid & 15;   // expert group: experts tx*4 .. tx*4+3
  const int ty   = tid >> 4;   // token group : tokens  ty*8 .. ty*8+7
  const int tok0 = blockIdx.x * TM;

  if (tid < NEXP) cnt_s[tid] = 0;

  // ---- per-thread staging coordinates (swizzled source, linear LDS dest) ----
  int pA[4], pB[2];
  const float* srcA[4];
  const float* srcB[2];
#pragma unroll
  for (int q = 0; q < 4; ++q) {
    int p = q * 256 + tid;          // linear float4 position in A tile
    pA[q] = p;
    int r = p >> 3, sc = p & 7;
    int s = sc ^ ((r >> 2) & 7);    // original slot stored at this position
    srcA[q] = x + (size_t)(tok0 + r) * DIM + s * 4;
  }
#pragma unroll
  for (int q = 0; q < 2; ++q) {
    int p = q * 256 + tid;
    pB[q] = p;
    int r = p >> 3, sc = p & 7;
    int s = sc ^ ((r >> 2) & 7);
    srcB[q] = Wg + (size_t)r * DIM + s * 4;
  }

  float acc[8][4];
#pragma unroll
  for (int i = 0; i < 8; ++i)
#pragma unroll
    for (int j = 0; j < 4; ++j) acc[i][j] = 0.f;

  // ---- prologue: stage buf 0 ----
#pragma unroll
  for (int q = 0; q < 4; ++q) { gload16(srcA[q], &Xs4[0][pA[q]]); srcA[q] += BK; }
#pragma unroll
  for (int q = 0; q < 2; ++q) { gload16(srcB[q], &Ws4[0][pB[q]]); srcB[q] += BK; }

  // ---- main K loop: 2-phase double-buffer, counted vmcnt, raw barriers ----
  for (int it = 0; it < KITERS; ++it) {
    const int b = it & 1;
    if (it < KITERS - 1) {
#pragma unroll
      for (int q = 0; q < 4; ++q) { gload16(srcA[q], &Xs4[b ^ 1][pA[q]]); srcA[q] += BK; }
#pragma unroll
      for (int q = 0; q < 2; ++q) { gload16(srcB[q], &Ws4[b ^ 1][pB[q]]); srcB[q] += BK; }
      asm volatile("s_waitcnt vmcnt(6)" ::: "memory");  // 6 newest (next tile) stay in flight
    } else {
      asm volatile("s_waitcnt vmcnt(0)" ::: "memory");
    }
    __builtin_amdgcn_s_barrier();
    asm volatile("" ::: "memory");

#pragma unroll
    for (int dd = 0; dd < BK; dd += 4) {
      const int sidx = dd >> 2;
      float4 wv[4];
#pragma unroll
      for (int j = 0; j < 4; ++j) wv[j] = Ws4[b][swz(tx * 4 + j, sidx)];
#pragma unroll
      for (int i = 0; i < 8; ++i) {
        float4 xv = Xs4[b][swz(ty * 8 + i, sidx)];
#pragma unroll
        for (int j = 0; j < 4; ++j) {
          acc[i][j] = fmaf(xv.x, wv[j].x, acc[i][j]);
          acc[i][j] = fmaf(xv.y, wv[j].y, acc[i][j]);
          acc[i][j] = fmaf(xv.z, wv[j].z, acc[i][j]);
          acc[i][j] = fmaf(xv.w, wv[j].w, acc[i][j]);
        }
      }
    }
    asm volatile("" ::: "memory");
    __builtin_amdgcn_s_barrier();
    asm volatile("" ::: "memory");
  }

  // ---- epilogue: gather logits in LDS ----
#pragma unroll
  for (int i = 0; i < 8; ++i)
#pragma unroll
    for (int j = 0; j < 4; ++j)
      L[(ty * 8 + i) * 65 + tx * 4 + j] = acc[i][j];
  __syncthreads();

  // per-token softmax + top2 (thread = token; bank-conflict-free via stride 65)
  if (tid < TM) {
    const int base = tid * 65;
    float v1 = -1e30f, v2 = -1e30f;
    int i1 = 0, i2 = 0;
    for (int e = 0; e < NEXP; ++e) {
      float v = L[base + e];
      if (v > v1)      { v2 = v1; i2 = i1; v1 = v; i1 = e; }
      else if (v > v2) { v2 = v;  i2 = e; }
    }
    float ssum = 0.f;
    for (int e = 0; e < NEXP; ++e) {
      float p = __expf(L[base + e] - v1);
      ssum += p;
      L[base + e] = p;                    // store numerators back
    }
    Linv[tid] = 1.f / ssum;

    float e2   = __expf(v2 - v1);
    float invn = 1.f / (1.f + e2);        // == p1/(p1+p2) after softmax renorm
    const int g = tok0 + tid;
    out[2 * g]     = invn;
    out[2 * g + 1] = e2 * invn;
    out[2 * N_TOK + 2 * g]     = (float)i1;
    out[2 * N_TOK + 2 * g + 1] = (float)i2;
    atomicAdd(&cnt_s[i1], 1u);
    atomicAdd(&cnt_s[i2], 1u);
  }
  __syncthreads();

  // column sums of probs (mean gate prob numerator), 4 partials per expert
  {
    const int e = tid & 63;
    const int q = tid >> 6;
    float s = 0.f;
#pragma unroll 4
    for (int t = 0; t < 32; ++t) {
      int row = q * 32 + t;
      s += L[row * 65 + e] * Linv[row];
    }
    colpart[q * 64 + e] = s;
  }
  __syncthreads();
  if (tid < NEXP) {
    float tot = colpart[tid] + colpart[64 + tid] + colpart[128 + tid] + colpart[192 + tid];
    atomicAdd(&sp_g[tid], tot);
    atomicAdd(&cnt_g[tid], cnt_s[tid]);
  }
}

__global__ void aux_kernel(const unsigned int* __restrict__ cnt,
                           const float* __restrict__ sp,
                           float* __restrict__ out) {
  const int l = threadIdx.x;  // 64 threads = 1 wave
  float v = (float)cnt[l] * sp[l];
#pragma unroll
  for (int off = 32; off > 0; off >>= 1) v += __shfl_down(v, off);
  if (l == 0)
    out[4 * N_TOK] = (float)NEXP * v * (1.f / (float)N_TOK) * (1.f / (float)N_TOK);
}

extern "C" void kernel_launch(void* const* d_in, const int* in_sizes, int n_in,
                              void* d_out, int out_size, void* d_ws, size_t ws_size,
                              hipStream_t stream) {
  const float* x  = (const float*)d_in[0];
  const float* Wg = (const float*)d_in[1];
  float* out = (float*)d_out;
  unsigned int* cnt = (unsigned int*)d_ws;
  float* sp = (float*)((char*)d_ws + 256);

  hipMemsetAsync(d_ws, 0, 512, stream);  // zero cnt[64] + sp[64]
  router_kernel<<<dim3(N_TOK / TM), dim3(NTHR), 0, stream>>>(x, Wg, out, cnt, sp);
  aux_kernel<<<dim3(1), dim3(64), 0, stream>>>(cnt, sp, out);
}